// Round 1
// baseline (3232.892 us; speedup 1.0000x reference)
//
#include <hip/hip_runtime.h>

// ---------------------------------------------------------------------------
// GCN forward on MI355X.
// Pipeline:
//   1. degcnt[v]  = #incoming edges (int atomics), dinv = rsqrt(deg+1)
//   2. hA = embed_table[x]                     (gather, fully overwritten)
//   3. hB = hA @ W1                            (LDS-staged fp32 GEMM)
//   4. hA = 0 ; scatter: hA[dst] += dinv[s]*dinv[d] * hB[src]   (fp32 HW atomics)
//   5. hA = relu(hA + dinv^2*hB + b1)          (self-loop folded here)
//   6-8. repeat with W2/b2
//   9. per-node: p = hA[i] @ Wlin (2 dots), atomicAdd into per-graph acc + count
//  10. out[g][c] = acc[g][c]/max(cnt,1) + blin[c]
// ---------------------------------------------------------------------------

#define DD 64          // feature dim
#define DQ 16          // float4s per row

static __device__ __forceinline__ void atomAddF(float* p, float v) {
    unsafeAtomicAdd(p, v);   // global_atomic_add_f32 on gfx950
}

__global__ void deg_count_kernel(const int* __restrict__ dst, int E,
                                 int* __restrict__ degcnt) {
    int e = blockIdx.x * blockDim.x + threadIdx.x;
    if (e < E) atomicAdd(&degcnt[dst[e]], 1);
}

__global__ void dinv_kernel(const int* __restrict__ degcnt, int N,
                            float* __restrict__ dinv) {
    int i = blockIdx.x * blockDim.x + threadIdx.x;
    if (i < N) dinv[i] = rsqrtf((float)degcnt[i] + 1.0f);
}

__global__ void embed_kernel(const int* __restrict__ x,
                             const float4* __restrict__ table,
                             float4* __restrict__ hA, int N) {
    int t = blockIdx.x * blockDim.x + threadIdx.x;
    if (t < N * DQ) {
        int i = t >> 4, j = t & 15;
        hA[t] = table[(size_t)x[i] * DQ + j];
    }
}

// hB[N,64] = hA[N,64] @ W[64,64].  Block: 256 thr = 4 waves; 16 rows/block.
__global__ __launch_bounds__(256) void gemm_kernel(
        const float* __restrict__ hA, const float* __restrict__ W,
        float* __restrict__ hB, int N) {
    __shared__ float Ws[DD * DD];   // 16 KB
    __shared__ float Hs[16 * DD];   // 4 KB
    int row0 = blockIdx.x * 16;
    int tid = threadIdx.x;
    for (int k = tid; k < DD * DD; k += 256) Ws[k] = W[k];
    for (int k = tid; k < 16 * DD; k += 256) {
        int r = row0 + (k >> 6);
        Hs[k] = (r < N) ? hA[(size_t)row0 * DD + k] : 0.0f;
    }
    __syncthreads();
    int wave = tid >> 6, lane = tid & 63;
    for (int rr = 0; rr < 4; ++rr) {
        int row = wave * 4 + rr;
        if (row0 + row >= N) break;
        float acc = 0.0f;
        #pragma unroll
        for (int k = 0; k < DD; ++k)
            acc = fmaf(Hs[row * DD + k], Ws[k * DD + lane], acc);
        hB[(size_t)(row0 + row) * DD + lane] = acc;
    }
}

// 16 threads per edge, float4 per thread: hA[dst] += w * hB[src]
__global__ void scatter_kernel(const int* __restrict__ src,
                               const int* __restrict__ dst,
                               const float* __restrict__ dinv,
                               const float4* __restrict__ hB,
                               float* __restrict__ hA, int E) {
    int t = blockIdx.x * blockDim.x + threadIdx.x;
    if (t >= E * DQ) return;
    int e = t >> 4, j = t & 15;
    int s = src[e], d = dst[e];
    float w = dinv[s] * dinv[d];
    float4 v = hB[(size_t)s * DQ + j];
    float* p = hA + (size_t)d * DD + j * 4;
    atomAddF(p + 0, w * v.x);
    atomAddF(p + 1, w * v.y);
    atomAddF(p + 2, w * v.z);
    atomAddF(p + 3, w * v.w);
}

// hA = relu(hA + dinv^2 * hB + bias)
__global__ void fixup_kernel(float4* __restrict__ hA,
                             const float4* __restrict__ hB,
                             const float* __restrict__ dinv,
                             const float* __restrict__ bias, int N) {
    int t = blockIdx.x * blockDim.x + threadIdx.x;
    if (t >= N * DQ) return;
    int i = t >> 4, j = t & 15;
    float w = dinv[i] * dinv[i];
    float4 a = hA[t], b = hB[t];
    float4 bb = ((const float4*)bias)[j];
    a.x = fmaxf(a.x + w * b.x + bb.x, 0.0f);
    a.y = fmaxf(a.y + w * b.y + bb.y, 0.0f);
    a.z = fmaxf(a.z + w * b.z + bb.z, 0.0f);
    a.w = fmaxf(a.w + w * b.w + bb.w, 0.0f);
    hA[t] = a;
}

// per-node: two 64-dots vs Wlin, reduce across 16-lane group, atomics to graph acc
__global__ void pool_kernel(const float4* __restrict__ hA,
                            const int* __restrict__ batch,
                            const float* __restrict__ Wlin,
                            float* __restrict__ outacc,
                            float* __restrict__ cnt, int N) {
    int t = blockIdx.x * blockDim.x + threadIdx.x;
    if (t >= N * DQ) return;
    int i = t >> 4, j = t & 15;
    float4 v = hA[t];
    int d0 = j * 4;
    float p0 = v.x * Wlin[(d0 + 0) * 2] + v.y * Wlin[(d0 + 1) * 2] +
               v.z * Wlin[(d0 + 2) * 2] + v.w * Wlin[(d0 + 3) * 2];
    float p1 = v.x * Wlin[(d0 + 0) * 2 + 1] + v.y * Wlin[(d0 + 1) * 2 + 1] +
               v.z * Wlin[(d0 + 2) * 2 + 1] + v.w * Wlin[(d0 + 3) * 2 + 1];
    #pragma unroll
    for (int off = 8; off >= 1; off >>= 1) {
        p0 += __shfl_xor(p0, off);
        p1 += __shfl_xor(p1, off);
    }
    if (j == 0) {
        int b = batch[i];
        atomAddF(&outacc[b * 2 + 0], p0);
        atomAddF(&outacc[b * 2 + 1], p1);
        atomAddF(&cnt[b], 1.0f);
    }
}

__global__ void final_kernel(const float* __restrict__ outacc,
                             const float* __restrict__ cnt,
                             const float* __restrict__ blin,
                             float* __restrict__ out, int G) {
    int t = blockIdx.x * blockDim.x + threadIdx.x;
    if (t >= G * 2) return;
    int g = t >> 1, c = t & 1;
    out[t] = outacc[t] / fmaxf(cnt[g], 1.0f) + blin[c];
}

extern "C" void kernel_launch(void* const* d_in, const int* in_sizes, int n_in,
                              void* d_out, int out_size, void* d_ws, size_t ws_size,
                              hipStream_t stream) {
    const int*   x      = (const int*)d_in[0];
    const int*   ei     = (const int*)d_in[1];   // [2,E] row-major
    // d_in[2] = edge_type (unused by reference)
    const int*   batch  = (const int*)d_in[3];
    const float* table  = (const float*)d_in[4];
    const float* W1     = (const float*)d_in[5];
    const float* b1     = (const float*)d_in[6];
    const float* W2     = (const float*)d_in[7];
    const float* b2     = (const float*)d_in[8];
    const float* Wlin   = (const float*)d_in[9];
    const float* blin   = (const float*)d_in[10];
    float* out = (float*)d_out;

    const int N = in_sizes[0];
    const int E = in_sizes[2];          // edge_type count == E
    const int G = out_size / 2;

    const int* src = ei;
    const int* dst = ei + E;

    // workspace layout
    size_t nh = (size_t)N * DD;
    float* hA     = (float*)d_ws;
    float* hB     = hA + nh;
    float* dinv   = hB + nh;
    int*   degcnt = (int*)(dinv + N);
    float* outacc = (float*)(degcnt + N);
    float* cnt    = outacc + (size_t)G * 2;

    const int BT = 256;
    int gE   = (E + BT - 1) / BT;
    int gN   = (N + BT - 1) / BT;
    int gN16 = ((N * DQ) + BT - 1) / BT;
    int gE16 = ((E * DQ) + BT - 1) / BT;
    int gRow = (N + 15) / 16;

    // degree + dinv
    hipMemsetAsync(degcnt, 0, (size_t)N * sizeof(int), stream);
    hipMemsetAsync(outacc, 0, (size_t)G * 3 * sizeof(float), stream);
    deg_count_kernel<<<gE, BT, 0, stream>>>(dst, E, degcnt);
    dinv_kernel<<<gN, BT, 0, stream>>>(degcnt, N, dinv);

    // embed
    embed_kernel<<<gN16, BT, 0, stream>>>(x, (const float4*)table, (float4*)hA, N);

    // layer 1
    gemm_kernel<<<gRow, BT, 0, stream>>>(hA, W1, hB, N);
    hipMemsetAsync(hA, 0, nh * sizeof(float), stream);
    scatter_kernel<<<gE16, BT, 0, stream>>>(src, dst, dinv, (const float4*)hB, hA, E);
    fixup_kernel<<<gN16, BT, 0, stream>>>((float4*)hA, (const float4*)hB, dinv, b1, N);

    // layer 2
    gemm_kernel<<<gRow, BT, 0, stream>>>(hA, W2, hB, N);
    hipMemsetAsync(hA, 0, nh * sizeof(float), stream);
    scatter_kernel<<<gE16, BT, 0, stream>>>(src, dst, dinv, (const float4*)hB, hA, E);
    fixup_kernel<<<gN16, BT, 0, stream>>>((float4*)hA, (const float4*)hB, dinv, b2, N);

    // pool + linear
    pool_kernel<<<gN16, BT, 0, stream>>>((const float4*)hA, batch, Wlin, outacc, cnt, N);
    final_kernel<<<(G * 2 + BT - 1) / BT, BT, 0, stream>>>(outacc, cnt, blin, out, G);
}

// Round 2
// 785.218 us; speedup vs baseline: 4.1172x; 4.1172x over previous
//
#include <hip/hip_runtime.h>

// ---------------------------------------------------------------------------
// GCN forward on MI355X — round 2: CSR gather instead of atomic scatter.
//
//   1. degcnt[v] = #incoming edges (int atomics)
//   2. dinv = rsqrt(deg+1)
//   3. wave-scan of degcnt -> cursor[] = exclusive row base (one global ctr)
//   4. fill: p = atomicAdd(cursor[dst]); csr_src[p] = src   (cursor -> row END)
//   5. hA = embed_table[x]
//   6. hB = hA @ W1 (LDS GEMM); hA = gather(hB) + selfloop + bias + relu
//   7. hB = hA @ W2;            hA = gather(hB) + selfloop + bias + relu
//   8. pool (fold Wlin at node level) + final divide
// ---------------------------------------------------------------------------

#define DD 64          // feature dim
#define DQ 16          // float4s per row

static __device__ __forceinline__ void atomAddF(float* p, float v) {
    unsafeAtomicAdd(p, v);   // global_atomic_add_f32 on gfx950
}

__global__ void deg_count_kernel(const int* __restrict__ dst, int E,
                                 int* __restrict__ degcnt) {
    int e = blockIdx.x * blockDim.x + threadIdx.x;
    if (e < E) atomicAdd(&degcnt[dst[e]], 1);
}

__global__ void dinv_kernel(const int* __restrict__ degcnt, int N,
                            float* __restrict__ dinv) {
    int i = blockIdx.x * blockDim.x + threadIdx.x;
    if (i < N) dinv[i] = rsqrtf((float)degcnt[i] + 1.0f);
}

// one wave per block; exclusive row bases via wave scan + single global counter
__global__ __launch_bounds__(64) void scan_kernel(const int* __restrict__ deg,
                                                  int* __restrict__ cursor,
                                                  int* __restrict__ gcount, int N) {
    int lane = threadIdx.x;
    int i = blockIdx.x * 64 + lane;
    int d = (i < N) ? deg[i] : 0;
    int sum = d;
    #pragma unroll
    for (int off = 1; off < 64; off <<= 1) {
        int t = __shfl_up(sum, off);
        if (lane >= off) sum += t;
    }
    int base = 0;
    if (lane == 63) base = atomicAdd(gcount, sum);
    base = __shfl(base, 63);
    if (i < N) cursor[i] = base + sum - d;   // exclusive
}

__global__ void fill_kernel(const int* __restrict__ src,
                            const int* __restrict__ dst,
                            int* __restrict__ cursor,
                            int* __restrict__ csr_src, int E) {
    int e = blockIdx.x * blockDim.x + threadIdx.x;
    if (e < E) {
        int p = atomicAdd(&cursor[dst[e]], 1);
        csr_src[p] = src[e];
    }
}

__global__ void embed_kernel(const int* __restrict__ x,
                             const float4* __restrict__ table,
                             float4* __restrict__ hA, int N) {
    int t = blockIdx.x * blockDim.x + threadIdx.x;
    if (t < N * DQ) {
        int i = t >> 4, j = t & 15;
        hA[t] = table[(size_t)x[i] * DQ + j];
    }
}

// hB[N,64] = hA[N,64] @ W[64,64].  Block: 256 thr = 4 waves; 16 rows/block.
__global__ __launch_bounds__(256) void gemm_kernel(
        const float* __restrict__ hA, const float* __restrict__ W,
        float* __restrict__ hB, int N) {
    __shared__ float Ws[DD * DD];   // 16 KB
    __shared__ float Hs[16 * DD];   // 4 KB
    int row0 = blockIdx.x * 16;
    int tid = threadIdx.x;
    for (int k = tid; k < DD * DD; k += 256) Ws[k] = W[k];
    for (int k = tid; k < 16 * DD; k += 256) {
        int r = row0 + (k >> 6);
        Hs[k] = (r < N) ? hA[(size_t)row0 * DD + k] : 0.0f;
    }
    __syncthreads();
    int wave = tid >> 6, lane = tid & 63;
    for (int rr = 0; rr < 4; ++rr) {
        int row = wave * 4 + rr;
        if (row0 + row >= N) break;
        float acc = 0.0f;
        #pragma unroll
        for (int k = 0; k < DD; ++k)
            acc = fmaf(Hs[row * DD + k], Ws[k * DD + lane], acc);
        hB[(size_t)(row0 + row) * DD + lane] = acc;
    }
}

// 16 lanes per node: pull neighbor rows, add self-loop + bias, relu.
__global__ __launch_bounds__(256) void gather_kernel(
        const int* __restrict__ cursorEnd,   // post-fill cursor = row end
        const int* __restrict__ deg,
        const int* __restrict__ csr_src,
        const float* __restrict__ dinv,
        const float4* __restrict__ hB,
        const float* __restrict__ bias,
        float4* __restrict__ outA, int N) {
    int t = blockIdx.x * blockDim.x + threadIdx.x;
    if (t >= N * DQ) return;
    int node = t >> 4, j = t & 15;
    int end = cursorEnd[node];
    int dg  = deg[node];
    int begin = end - dg;
    float di = dinv[node];

    float4 v = hB[(size_t)node * DQ + j];   // self loop
    float w0 = di * di;
    float4 acc;
    acc.x = w0 * v.x; acc.y = w0 * v.y; acc.z = w0 * v.z; acc.w = w0 * v.w;

    for (int k = begin; k < end; ++k) {
        int s = csr_src[k];
        float w = di * dinv[s];
        float4 u = hB[(size_t)s * DQ + j];
        acc.x = fmaf(w, u.x, acc.x);
        acc.y = fmaf(w, u.y, acc.y);
        acc.z = fmaf(w, u.z, acc.z);
        acc.w = fmaf(w, u.w, acc.w);
    }
    float4 bb = ((const float4*)bias)[j];
    acc.x = fmaxf(acc.x + bb.x, 0.0f);
    acc.y = fmaxf(acc.y + bb.y, 0.0f);
    acc.z = fmaxf(acc.z + bb.z, 0.0f);
    acc.w = fmaxf(acc.w + bb.w, 0.0f);
    outA[(size_t)node * DQ + j] = acc;
}

// per-node: two 64-dots vs Wlin, reduce across 16-lane group, atomics to graph acc
__global__ void pool_kernel(const float4* __restrict__ hA,
                            const int* __restrict__ batch,
                            const float* __restrict__ Wlin,
                            float* __restrict__ outacc,
                            float* __restrict__ cnt, int N) {
    int t = blockIdx.x * blockDim.x + threadIdx.x;
    if (t >= N * DQ) return;
    int i = t >> 4, j = t & 15;
    float4 v = hA[t];
    int d0 = j * 4;
    float p0 = v.x * Wlin[(d0 + 0) * 2] + v.y * Wlin[(d0 + 1) * 2] +
               v.z * Wlin[(d0 + 2) * 2] + v.w * Wlin[(d0 + 3) * 2];
    float p1 = v.x * Wlin[(d0 + 0) * 2 + 1] + v.y * Wlin[(d0 + 1) * 2 + 1] +
               v.z * Wlin[(d0 + 2) * 2 + 1] + v.w * Wlin[(d0 + 3) * 2 + 1];
    #pragma unroll
    for (int off = 8; off >= 1; off >>= 1) {
        p0 += __shfl_xor(p0, off);
        p1 += __shfl_xor(p1, off);
    }
    if (j == 0) {
        int b = batch[i];
        atomAddF(&outacc[b * 2 + 0], p0);
        atomAddF(&outacc[b * 2 + 1], p1);
        atomAddF(&cnt[b], 1.0f);
    }
}

__global__ void final_kernel(const float* __restrict__ outacc,
                             const float* __restrict__ cnt,
                             const float* __restrict__ blin,
                             float* __restrict__ out, int G) {
    int t = blockIdx.x * blockDim.x + threadIdx.x;
    if (t >= G * 2) return;
    int g = t >> 1, c = t & 1;
    out[t] = outacc[t] / fmaxf(cnt[g], 1.0f) + blin[c];
}

extern "C" void kernel_launch(void* const* d_in, const int* in_sizes, int n_in,
                              void* d_out, int out_size, void* d_ws, size_t ws_size,
                              hipStream_t stream) {
    const int*   x      = (const int*)d_in[0];
    const int*   ei     = (const int*)d_in[1];   // [2,E] row-major
    const int*   batch  = (const int*)d_in[3];
    const float* table  = (const float*)d_in[4];
    const float* W1     = (const float*)d_in[5];
    const float* b1     = (const float*)d_in[6];
    const float* W2     = (const float*)d_in[7];
    const float* b2     = (const float*)d_in[8];
    const float* Wlin   = (const float*)d_in[9];
    const float* blin   = (const float*)d_in[10];
    float* out = (float*)d_out;

    const int N = in_sizes[0];
    const int E = in_sizes[2];          // edge_type count == E
    const int G = out_size / 2;

    const int* src = ei;
    const int* dst = ei + E;

    // workspace layout
    size_t nh = (size_t)N * DD;
    float* hA      = (float*)d_ws;
    float* hB      = hA + nh;
    float* dinv    = hB + nh;
    int*   degcnt  = (int*)(dinv + N);
    int*   cursor  = degcnt + N;
    int*   csr_src = cursor + N;
    int*   gcount  = csr_src + E;
    float* outacc  = (float*)(gcount + 1);
    float* cnt     = outacc + (size_t)G * 2;

    const int BT = 256;
    int gE   = (E + BT - 1) / BT;
    int gN   = (N + BT - 1) / BT;
    int gN16 = ((N * DQ) + BT - 1) / BT;
    int gW   = (N + 63) / 64;
    int gRow = (N + 15) / 16;

    hipMemsetAsync(degcnt, 0, (size_t)N * sizeof(int), stream);
    hipMemsetAsync(gcount, 0, sizeof(int), stream);
    hipMemsetAsync(outacc, 0, (size_t)G * 3 * sizeof(float), stream);

    // degree, norm, CSR
    deg_count_kernel<<<gE, BT, 0, stream>>>(dst, E, degcnt);
    dinv_kernel<<<gN, BT, 0, stream>>>(degcnt, N, dinv);
    scan_kernel<<<gW, 64, 0, stream>>>(degcnt, cursor, gcount, N);
    fill_kernel<<<gE, BT, 0, stream>>>(src, dst, cursor, csr_src, E);

    // embed
    embed_kernel<<<gN16, BT, 0, stream>>>(x, (const float4*)table, (float4*)hA, N);

    // layer 1
    gemm_kernel<<<gRow, BT, 0, stream>>>(hA, W1, hB, N);
    gather_kernel<<<gN16, BT, 0, stream>>>(cursor, degcnt, csr_src, dinv,
                                           (const float4*)hB, b1, (float4*)hA, N);
    // layer 2
    gemm_kernel<<<gRow, BT, 0, stream>>>(hA, W2, hB, N);
    gather_kernel<<<gN16, BT, 0, stream>>>(cursor, degcnt, csr_src, dinv,
                                           (const float4*)hB, b2, (float4*)hA, N);

    // pool + linear
    pool_kernel<<<gN16, BT, 0, stream>>>((const float4*)hA, batch, Wlin, outacc, cnt, N);
    final_kernel<<<(G * 2 + BT - 1) / BT, BT, 0, stream>>>(outacc, cnt, blin, out, G);
}

// Round 3
// 624.345 us; speedup vs baseline: 5.1781x; 1.2577x over previous
//
#include <hip/hip_runtime.h>

// ---------------------------------------------------------------------------
// GCN forward on MI355X — round 3: fused layer kernels (aggregate -> GEMM),
// pool folded into layer 2 with block-segmented atomics, counts by bsearch.
//
//   1. degcnt[v] = #incoming edges; dinv = rsqrt(deg+1); CSR build
//   2. hA = embed_table[x]
//   3. layer1: per 16-node block: LDS agg = sum w*hA[src] + selfloop,
//              then agg @ W1 + b1, relu -> hB
//   4. layer2: same from hB with W2/b2, then fold Wlin dot + per-graph
//              segmented atomic accumulation (batch is sorted)
//   5. final: cnt[g] via binary search on sorted batch; divide + blin
// ---------------------------------------------------------------------------

#define DD 64          // feature dim
#define DQ 16          // float4s per row

static __device__ __forceinline__ void atomAddF(float* p, float v) {
    unsafeAtomicAdd(p, v);   // global_atomic_add_f32 on gfx950
}

__global__ void deg_count_kernel(const int* __restrict__ dst, int E,
                                 int* __restrict__ degcnt) {
    int e = blockIdx.x * blockDim.x + threadIdx.x;
    if (e < E) atomicAdd(&degcnt[dst[e]], 1);
}

__global__ void dinv_kernel(const int* __restrict__ degcnt, int N,
                            float* __restrict__ dinv) {
    int i = blockIdx.x * blockDim.x + threadIdx.x;
    if (i < N) dinv[i] = rsqrtf((float)degcnt[i] + 1.0f);
}

// one wave per block; exclusive row bases via wave scan + single global counter
__global__ __launch_bounds__(64) void scan_kernel(const int* __restrict__ deg,
                                                  int* __restrict__ cursor,
                                                  int* __restrict__ gcount, int N) {
    int lane = threadIdx.x;
    int i = blockIdx.x * 64 + lane;
    int d = (i < N) ? deg[i] : 0;
    int sum = d;
    #pragma unroll
    for (int off = 1; off < 64; off <<= 1) {
        int t = __shfl_up(sum, off);
        if (lane >= off) sum += t;
    }
    int base = 0;
    if (lane == 63) base = atomicAdd(gcount, sum);
    base = __shfl(base, 63);
    if (i < N) cursor[i] = base + sum - d;   // exclusive
}

__global__ void fill_kernel(const int* __restrict__ src,
                            const int* __restrict__ dst,
                            int* __restrict__ cursor,
                            int* __restrict__ csr_src, int E) {
    int e = blockIdx.x * blockDim.x + threadIdx.x;
    if (e < E) {
        int p = atomicAdd(&cursor[dst[e]], 1);
        csr_src[p] = src[e];
    }
}

__global__ void embed_kernel(const int* __restrict__ x,
                             const float4* __restrict__ table,
                             float4* __restrict__ hA, int N) {
    int t = blockIdx.x * blockDim.x + threadIdx.x;
    if (t < N * DQ) {
        int i = t >> 4, j = t & 15;
        hA[t] = table[(size_t)x[i] * DQ + j];
    }
}

// Phase A helper: 16 lanes per node gather-aggregate into float4.
static __device__ __forceinline__ float4 gather_agg(
        int node, int j,
        const int* __restrict__ cursorEnd, const int* __restrict__ deg,
        const int* __restrict__ csr_src, const float* __restrict__ dinv,
        const float4* __restrict__ hPrev) {
    int end = cursorEnd[node];
    int dg  = deg[node];
    int begin = end - dg;
    float di = dinv[node];
    float4 v = hPrev[(size_t)node * DQ + j];   // self loop
    float w0 = di * di;
    float4 acc;
    acc.x = w0 * v.x; acc.y = w0 * v.y; acc.z = w0 * v.z; acc.w = w0 * v.w;
    for (int k = begin; k < end; ++k) {
        int s = csr_src[k];
        float w = di * dinv[s];
        float4 u = hPrev[(size_t)s * DQ + j];
        acc.x = fmaf(w, u.x, acc.x);
        acc.y = fmaf(w, u.y, acc.y);
        acc.z = fmaf(w, u.z, acc.z);
        acc.w = fmaf(w, u.w, acc.w);
    }
    return acc;
}

// Layer: hNext[node] = relu( agg(hPrev)[node] @ W + b )
__global__ __launch_bounds__(256) void layer_kernel(
        const int* __restrict__ cursorEnd, const int* __restrict__ deg,
        const int* __restrict__ csr_src, const float* __restrict__ dinv,
        const float4* __restrict__ hPrev, const float* __restrict__ W,
        const float* __restrict__ bias, float* __restrict__ hNext, int N) {
    __shared__ float Ws[DD * DD];   // 16 KB
    __shared__ float Hs[16 * DD];   // 4 KB
    int row0 = blockIdx.x * 16;
    int tid = threadIdx.x;
    {   // stage W (vectorized)
        const float4* W4 = (const float4*)W;
        float4* Ws4 = (float4*)Ws;
        for (int k = tid; k < DD * DD / 4; k += 256) Ws4[k] = W4[k];
    }
    int node_l = tid >> 4, j = tid & 15;
    int node = row0 + node_l;
    float4 acc = make_float4(0.f, 0.f, 0.f, 0.f);
    if (node < N)
        acc = gather_agg(node, j, cursorEnd, deg, csr_src, dinv, hPrev);
    ((float4*)Hs)[node_l * DQ + j] = acc;
    __syncthreads();

    int wave = tid >> 6, lane = tid & 63;
    float b = bias[lane];
    #pragma unroll
    for (int rr = 0; rr < 4; ++rr) {
        int row = wave * 4 + rr;
        if (row0 + row >= N) break;
        float a = b;
        #pragma unroll
        for (int k = 0; k < DD; ++k)
            a = fmaf(Hs[row * DD + k], Ws[k * DD + lane], a);
        hNext[(size_t)(row0 + row) * DD + lane] = fmaxf(a, 0.0f);
    }
}

// Layer 2 fused with pool: compute h2 in registers, dot with Wlin,
// wave-reduce, block-segment by (sorted) batch, few atomics.
__global__ __launch_bounds__(256) void layer2_pool_kernel(
        const int* __restrict__ cursorEnd, const int* __restrict__ deg,
        const int* __restrict__ csr_src, const float* __restrict__ dinv,
        const float4* __restrict__ hPrev, const float* __restrict__ W,
        const float* __restrict__ bias, const int* __restrict__ batch,
        const float* __restrict__ Wlin, float* __restrict__ outacc, int N) {
    __shared__ float Ws[DD * DD];
    __shared__ float Hs[16 * DD];
    __shared__ float p0s[16], p1s[16];
    __shared__ int   bat[16];
    int row0 = blockIdx.x * 16;
    int tid = threadIdx.x;
    {
        const float4* W4 = (const float4*)W;
        float4* Ws4 = (float4*)Ws;
        for (int k = tid; k < DD * DD / 4; k += 256) Ws4[k] = W4[k];
    }
    int node_l = tid >> 4, j = tid & 15;
    int node = row0 + node_l;
    float4 acc = make_float4(0.f, 0.f, 0.f, 0.f);
    if (node < N)
        acc = gather_agg(node, j, cursorEnd, deg, csr_src, dinv, hPrev);
    ((float4*)Hs)[node_l * DQ + j] = acc;
    __syncthreads();

    int wave = tid >> 6, lane = tid & 63;
    float b   = bias[lane];
    float wl0 = Wlin[lane * 2 + 0];
    float wl1 = Wlin[lane * 2 + 1];
    #pragma unroll
    for (int rr = 0; rr < 4; ++rr) {
        int row = wave * 4 + rr;
        int grow = row0 + row;
        float p0 = 0.f, p1 = 0.f;
        if (grow < N) {
            float a = b;
            #pragma unroll
            for (int k = 0; k < DD; ++k)
                a = fmaf(Hs[row * DD + k], Ws[k * DD + lane], a);
            a = fmaxf(a, 0.0f);
            p0 = a * wl0;
            p1 = a * wl1;
        }
        #pragma unroll
        for (int off = 32; off >= 1; off >>= 1) {
            p0 += __shfl_xor(p0, off);
            p1 += __shfl_xor(p1, off);
        }
        if (lane == 0) {
            p0s[row] = p0;
            p1s[row] = p1;
            bat[row] = (grow < N) ? batch[grow] : -1;
        }
    }
    __syncthreads();
    if (tid < 16) {
        int bg = bat[tid];
        bool head = (bg >= 0) && (tid == 0 || bat[tid - 1] != bg);
        if (head) {
            float s0 = 0.f, s1 = 0.f;
            for (int k = tid; k < 16 && bat[k] == bg; ++k) {
                s0 += p0s[k];
                s1 += p1s[k];
            }
            atomAddF(&outacc[bg * 2 + 0], s0);
            atomAddF(&outacc[bg * 2 + 1], s1);
        }
    }
}

// counts via binary search on sorted batch; then divide + blin
__global__ void final_kernel(const float* __restrict__ outacc,
                             const int* __restrict__ batch,
                             const float* __restrict__ blin,
                             float* __restrict__ out, int G, int N) {
    int t = blockIdx.x * blockDim.x + threadIdx.x;
    if (t >= G * 2) return;
    int g = t >> 1, c = t & 1;
    int lo = 0, hi = N;
    while (lo < hi) { int m = (lo + hi) >> 1; if (batch[m] < g) lo = m + 1; else hi = m; }
    int lo2 = lo, hi2 = N;
    while (lo2 < hi2) { int m = (lo2 + hi2) >> 1; if (batch[m] < g + 1) lo2 = m + 1; else hi2 = m; }
    float cnt = (float)(lo2 - lo);
    out[t] = outacc[t] / fmaxf(cnt, 1.0f) + blin[c];
}

extern "C" void kernel_launch(void* const* d_in, const int* in_sizes, int n_in,
                              void* d_out, int out_size, void* d_ws, size_t ws_size,
                              hipStream_t stream) {
    const int*   x      = (const int*)d_in[0];
    const int*   ei     = (const int*)d_in[1];   // [2,E] row-major
    const int*   batch  = (const int*)d_in[3];
    const float* table  = (const float*)d_in[4];
    const float* W1     = (const float*)d_in[5];
    const float* b1     = (const float*)d_in[6];
    const float* W2     = (const float*)d_in[7];
    const float* b2     = (const float*)d_in[8];
    const float* Wlin   = (const float*)d_in[9];
    const float* blin   = (const float*)d_in[10];
    float* out = (float*)d_out;

    const int N = in_sizes[0];
    const int E = in_sizes[2];          // edge_type count == E
    const int G = out_size / 2;

    const int* src = ei;
    const int* dst = ei + E;

    // workspace layout
    size_t nh = (size_t)N * DD;
    float* hA      = (float*)d_ws;
    float* hB      = hA + nh;
    float* dinv    = hB + nh;
    int*   degcnt  = (int*)(dinv + N);
    int*   cursor  = degcnt + N;
    int*   csr_src = cursor + N;
    int*   gcount  = csr_src + E;
    float* outacc  = (float*)(gcount + 1);

    const int BT = 256;
    int gE   = (E + BT - 1) / BT;
    int gN   = (N + BT - 1) / BT;
    int gN16 = ((N * DQ) + BT - 1) / BT;
    int gW   = (N + 63) / 64;
    int gRow = (N + 15) / 16;

    hipMemsetAsync(degcnt, 0, (size_t)N * sizeof(int), stream);
    hipMemsetAsync(gcount, 0, sizeof(int), stream);
    hipMemsetAsync(outacc, 0, (size_t)G * 2 * sizeof(float), stream);

    // degree, norm, CSR
    deg_count_kernel<<<gE, BT, 0, stream>>>(dst, E, degcnt);
    dinv_kernel<<<gN, BT, 0, stream>>>(degcnt, N, dinv);
    scan_kernel<<<gW, 64, 0, stream>>>(degcnt, cursor, gcount, N);
    fill_kernel<<<gE, BT, 0, stream>>>(src, dst, cursor, csr_src, E);

    // embed
    embed_kernel<<<gN16, BT, 0, stream>>>(x, (const float4*)table, (float4*)hA, N);

    // layer 1 (fused agg + GEMM + relu)
    layer_kernel<<<gRow, BT, 0, stream>>>(cursor, degcnt, csr_src, dinv,
                                          (const float4*)hA, W1, b1, hB, N);
    // layer 2 (fused agg + GEMM + relu + pool)
    layer2_pool_kernel<<<gRow, BT, 0, stream>>>(cursor, degcnt, csr_src, dinv,
                                                (const float4*)hB, W2, b2,
                                                batch, Wlin, outacc, N);
    // final
    final_kernel<<<(G * 2 + BT - 1) / BT, BT, 0, stream>>>(outacc, batch, blin,
                                                           out, G, N);
}

// Round 4
// 560.136 us; speedup vs baseline: 5.7716x; 1.1146x over previous
//
#include <hip/hip_runtime.h>

// ---------------------------------------------------------------------------
// GCN forward on MI355X — round 4.
//  * layer 1 gathers straight from the (L2-resident, 2.56 MB) embedding table
//    via packed xd[v] = (dinv_v, x_v); no materialized h0.
//  * dinv folded into stored features: g1 = dinv * h1, so layer-2 gather is a
//    pure row sum (no per-edge dinv load/mul):
//       agg2_v = dinv_v * ( g1[v] + sum_{s in N(v)} g1[s] )
//  * gather loops unrolled 4-wide with 4 independent accumulators for MLP.
// ---------------------------------------------------------------------------

#define DD 64          // feature dim
#define DQ 16          // float4s per row

static __device__ __forceinline__ void atomAddF(float* p, float v) {
    unsafeAtomicAdd(p, v);   // global_atomic_add_f32 on gfx950
}

__global__ void deg_count_kernel(const int* __restrict__ dst, int E,
                                 int* __restrict__ degcnt) {
    int e = blockIdx.x * blockDim.x + threadIdx.x;
    if (e < E) atomicAdd(&degcnt[dst[e]], 1);
}

// xd[v] = (dinv_v, bitcast(x_v))
__global__ void prep_kernel(const int* __restrict__ degcnt,
                            const int* __restrict__ x,
                            float2* __restrict__ xd, int N) {
    int i = blockIdx.x * blockDim.x + threadIdx.x;
    if (i < N) {
        float di = rsqrtf((float)degcnt[i] + 1.0f);
        xd[i] = make_float2(di, __int_as_float(x[i]));
    }
}

// one wave per block; exclusive row bases via wave scan + single global counter
__global__ __launch_bounds__(64) void scan_kernel(const int* __restrict__ deg,
                                                  int* __restrict__ cursor,
                                                  int* __restrict__ gcount, int N) {
    int lane = threadIdx.x;
    int i = blockIdx.x * 64 + lane;
    int d = (i < N) ? deg[i] : 0;
    int sum = d;
    #pragma unroll
    for (int off = 1; off < 64; off <<= 1) {
        int t = __shfl_up(sum, off);
        if (lane >= off) sum += t;
    }
    int base = 0;
    if (lane == 63) base = atomicAdd(gcount, sum);
    base = __shfl(base, 63);
    if (i < N) cursor[i] = base + sum - d;   // exclusive
}

__global__ void fill_kernel(const int* __restrict__ src,
                            const int* __restrict__ dst,
                            int* __restrict__ cursor,
                            int* __restrict__ csr_src, int E) {
    int e = blockIdx.x * blockDim.x + threadIdx.x;
    if (e < E) {
        int p = atomicAdd(&cursor[dst[e]], 1);
        csr_src[p] = src[e];
    }
}

static __device__ __forceinline__ void f4fma(float4& a, float w, const float4& u) {
    a.x = fmaf(w, u.x, a.x); a.y = fmaf(w, u.y, a.y);
    a.z = fmaf(w, u.z, a.z); a.w = fmaf(w, u.w, a.w);
}
static __device__ __forceinline__ void f4add(float4& a, const float4& u) {
    a.x += u.x; a.y += u.y; a.z += u.z; a.w += u.w;
}

// ---------------- layer 1: agg from embedding table, write g1 = dinv*h1 ----
__global__ __launch_bounds__(256) void layer1_kernel(
        const int* __restrict__ cursorEnd, const int* __restrict__ deg,
        const int* __restrict__ csr_src, const float2* __restrict__ xd,
        const float4* __restrict__ table, const float* __restrict__ W,
        const float* __restrict__ bias, float* __restrict__ g1, int N) {
    __shared__ float Ws[DD * DD];   // 16 KB
    __shared__ float Hs[16 * DD];   // 4 KB
    __shared__ float dvs[16];
    int row0 = blockIdx.x * 16;
    int tid = threadIdx.x;
    {
        const float4* W4 = (const float4*)W;
        float4* Ws4 = (float4*)Ws;
        for (int k = tid; k < DD * DD / 4; k += 256) Ws4[k] = W4[k];
    }
    int node_l = tid >> 4, j = tid & 15;
    int node = row0 + node_l;
    float4 acc0 = make_float4(0.f, 0.f, 0.f, 0.f);
    float4 acc1 = acc0, acc2 = acc0, acc3 = acc0;
    if (node < N) {
        float2 sxd = xd[node];
        float di = sxd.x;
        int   xi = __float_as_int(sxd.y);
        if (j == 0) dvs[node_l] = di;
        // self term: dinv_v * t0[x_v]
        acc0 = table[(size_t)xi * DQ + j];
        acc0.x *= di; acc0.y *= di; acc0.z *= di; acc0.w *= di;
        int end = cursorEnd[node];
        int k = end - deg[node];
        for (; k + 3 < end; k += 4) {
            int s0 = csr_src[k], s1 = csr_src[k+1], s2 = csr_src[k+2], s3 = csr_src[k+3];
            float2 p0 = xd[s0], p1 = xd[s1], p2 = xd[s2], p3 = xd[s3];
            float4 u0 = table[(size_t)__float_as_int(p0.y) * DQ + j];
            float4 u1 = table[(size_t)__float_as_int(p1.y) * DQ + j];
            float4 u2 = table[(size_t)__float_as_int(p2.y) * DQ + j];
            float4 u3 = table[(size_t)__float_as_int(p3.y) * DQ + j];
            f4fma(acc0, p0.x, u0); f4fma(acc1, p1.x, u1);
            f4fma(acc2, p2.x, u2); f4fma(acc3, p3.x, u3);
        }
        for (; k < end; ++k) {
            int s = csr_src[k];
            float2 p = xd[s];
            float4 u = table[(size_t)__float_as_int(p.y) * DQ + j];
            f4fma(acc0, p.x, u);
        }
        f4add(acc0, acc1); f4add(acc2, acc3); f4add(acc0, acc2);
        // scale whole aggregate by dinv_v
        acc0.x *= di; acc0.y *= di; acc0.z *= di; acc0.w *= di;
    }
    ((float4*)Hs)[node_l * DQ + j] = acc0;
    __syncthreads();

    int wave = tid >> 6, lane = tid & 63;
    float b = bias[lane];
    #pragma unroll
    for (int rr = 0; rr < 4; ++rr) {
        int row = wave * 4 + rr;
        int grow = row0 + row;
        if (grow >= N) break;
        float a = b;
        #pragma unroll
        for (int k = 0; k < DD; ++k)
            a = fmaf(Hs[row * DD + k], Ws[k * DD + lane], a);
        g1[(size_t)grow * DD + lane] = dvs[row] * fmaxf(a, 0.0f);   // g1 = dinv*h1
    }
}

// -------- layer 2 + pool: agg2 = dinv_v*(g1[v] + sum g1[s]); h2@Wlin pooled --
__global__ __launch_bounds__(256) void layer2_pool_kernel(
        const int* __restrict__ cursorEnd, const int* __restrict__ deg,
        const int* __restrict__ csr_src, const float2* __restrict__ xd,
        const float4* __restrict__ g1, const float* __restrict__ W,
        const float* __restrict__ bias, const int* __restrict__ batch,
        const float* __restrict__ Wlin, float* __restrict__ outacc, int N) {
    __shared__ float Ws[DD * DD];
    __shared__ float Hs[16 * DD];
    __shared__ float p0s[16], p1s[16];
    __shared__ int   bat[16];
    int row0 = blockIdx.x * 16;
    int tid = threadIdx.x;
    {
        const float4* W4 = (const float4*)W;
        float4* Ws4 = (float4*)Ws;
        for (int k = tid; k < DD * DD / 4; k += 256) Ws4[k] = W4[k];
    }
    int node_l = tid >> 4, j = tid & 15;
    int node = row0 + node_l;
    float4 acc0 = make_float4(0.f, 0.f, 0.f, 0.f);
    float4 acc1 = acc0, acc2 = acc0, acc3 = acc0;
    if (node < N) {
        float di = xd[node].x;
        acc0 = g1[(size_t)node * DQ + j];    // self term, weight 1
        int end = cursorEnd[node];
        int k = end - deg[node];
        for (; k + 3 < end; k += 4) {
            int s0 = csr_src[k], s1 = csr_src[k+1], s2 = csr_src[k+2], s3 = csr_src[k+3];
            float4 u0 = g1[(size_t)s0 * DQ + j];
            float4 u1 = g1[(size_t)s1 * DQ + j];
            float4 u2 = g1[(size_t)s2 * DQ + j];
            float4 u3 = g1[(size_t)s3 * DQ + j];
            f4add(acc0, u0); f4add(acc1, u1); f4add(acc2, u2); f4add(acc3, u3);
        }
        for (; k < end; ++k)
            f4add(acc0, g1[(size_t)csr_src[k] * DQ + j]);
        f4add(acc0, acc1); f4add(acc2, acc3); f4add(acc0, acc2);
        acc0.x *= di; acc0.y *= di; acc0.z *= di; acc0.w *= di;
    }
    ((float4*)Hs)[node_l * DQ + j] = acc0;
    __syncthreads();

    int wave = tid >> 6, lane = tid & 63;
    float b   = bias[lane];
    float wl0 = Wlin[lane * 2 + 0];
    float wl1 = Wlin[lane * 2 + 1];
    #pragma unroll
    for (int rr = 0; rr < 4; ++rr) {
        int row = wave * 4 + rr;
        int grow = row0 + row;
        float p0 = 0.f, p1 = 0.f;
        if (grow < N) {
            float a = b;
            #pragma unroll
            for (int k = 0; k < DD; ++k)
                a = fmaf(Hs[row * DD + k], Ws[k * DD + lane], a);
            a = fmaxf(a, 0.0f);
            p0 = a * wl0;
            p1 = a * wl1;
        }
        #pragma unroll
        for (int off = 32; off >= 1; off >>= 1) {
            p0 += __shfl_xor(p0, off);
            p1 += __shfl_xor(p1, off);
        }
        if (lane == 0) {
            p0s[row] = p0;
            p1s[row] = p1;
            bat[row] = (grow < N) ? batch[grow] : -1;
        }
    }
    __syncthreads();
    if (tid < 16) {
        int bg = bat[tid];
        bool head = (bg >= 0) && (tid == 0 || bat[tid - 1] != bg);
        if (head) {
            float s0 = 0.f, s1 = 0.f;
            for (int k = tid; k < 16 && bat[k] == bg; ++k) {
                s0 += p0s[k];
                s1 += p1s[k];
            }
            atomAddF(&outacc[bg * 2 + 0], s0);
            atomAddF(&outacc[bg * 2 + 1], s1);
        }
    }
}

// counts via binary search on sorted batch; then divide + blin
__global__ void final_kernel(const float* __restrict__ outacc,
                             const int* __restrict__ batch,
                             const float* __restrict__ blin,
                             float* __restrict__ out, int G, int N) {
    int t = blockIdx.x * blockDim.x + threadIdx.x;
    if (t >= G * 2) return;
    int g = t >> 1, c = t & 1;
    int lo = 0, hi = N;
    while (lo < hi) { int m = (lo + hi) >> 1; if (batch[m] < g) lo = m + 1; else hi = m; }
    int lo2 = lo, hi2 = N;
    while (lo2 < hi2) { int m = (lo2 + hi2) >> 1; if (batch[m] < g + 1) lo2 = m + 1; else hi2 = m; }
    float cnt = (float)(lo2 - lo);
    out[t] = outacc[t] / fmaxf(cnt, 1.0f) + blin[c];
}

extern "C" void kernel_launch(void* const* d_in, const int* in_sizes, int n_in,
                              void* d_out, int out_size, void* d_ws, size_t ws_size,
                              hipStream_t stream) {
    const int*   x      = (const int*)d_in[0];
    const int*   ei     = (const int*)d_in[1];   // [2,E] row-major
    const int*   batch  = (const int*)d_in[3];
    const float* table  = (const float*)d_in[4];
    const float* W1     = (const float*)d_in[5];
    const float* b1     = (const float*)d_in[6];
    const float* W2     = (const float*)d_in[7];
    const float* b2     = (const float*)d_in[8];
    const float* Wlin   = (const float*)d_in[9];
    const float* blin   = (const float*)d_in[10];
    float* out = (float*)d_out;

    const int N = in_sizes[0];
    const int E = in_sizes[2];          // edge_type count == E
    const int G = out_size / 2;

    const int* src = ei;
    const int* dst = ei + E;

    // workspace layout
    size_t nh = (size_t)N * DD;
    float*  g1      = (float*)d_ws;
    float2* xd      = (float2*)(g1 + nh);
    int*    degcnt  = (int*)(xd + N);
    int*    cursor  = degcnt + N;
    int*    csr_src = cursor + N;
    int*    gcount  = csr_src + E;
    float*  outacc  = (float*)(gcount + 1);

    const int BT = 256;
    int gE   = (E + BT - 1) / BT;
    int gN   = (N + BT - 1) / BT;
    int gW   = (N + 63) / 64;
    int gRow = (N + 15) / 16;

    hipMemsetAsync(degcnt, 0, (size_t)N * sizeof(int), stream);
    hipMemsetAsync(gcount, 0, sizeof(int), stream);
    hipMemsetAsync(outacc, 0, (size_t)G * 2 * sizeof(float), stream);

    // degree, norm+pack, CSR
    deg_count_kernel<<<gE, BT, 0, stream>>>(dst, E, degcnt);
    prep_kernel<<<gN, BT, 0, stream>>>(degcnt, x, xd, N);
    scan_kernel<<<gW, 64, 0, stream>>>(degcnt, cursor, gcount, N);
    fill_kernel<<<gE, BT, 0, stream>>>(src, dst, cursor, csr_src, E);

    // layer 1 (embed+agg+GEMM+relu fused; writes g1 = dinv*h1)
    layer1_kernel<<<gRow, BT, 0, stream>>>(cursor, degcnt, csr_src, xd,
                                           (const float4*)table, W1, b1, g1, N);
    // layer 2 (agg+GEMM+relu+pool fused)
    layer2_pool_kernel<<<gRow, BT, 0, stream>>>(cursor, degcnt, csr_src, xd,
                                                (const float4*)g1, W2, b2,
                                                batch, Wlin, outacc, N);
    // final
    final_kernel<<<(G * 2 + BT - 1) / BT, BT, 0, stream>>>(outacc, batch, blin,
                                                           out, G, N);
}

// Round 5
// 425.590 us; speedup vs baseline: 7.5963x; 1.3161x over previous
//
#include <hip/hip_runtime.h>

// ---------------------------------------------------------------------------
// GCN forward on MI355X — round 5.
//  * CSR build replaced by bucketed counting sort (no per-node global atomics,
//    all scatter writes line-merged in L2):
//      bin_count -> scan -> fill_pairs (bucket append) -> build_csr (per-bucket
//      LDS count/scan/scatter; also emits degcnt, cursor, xd coalesced)
//  * layer gathers: branchless masked 4-wide inner loop (no serial tail).
//  * layer1 gathers from L2-resident embedding table; g1 = dinv*h1 folding;
//    layer2 fused with pool (block-segmented atomics, sorted batch).
// ---------------------------------------------------------------------------

#define DD 64          // feature dim
#define DQ 16          // float4s per row
#define BKT 256        // nodes per bucket
#define MAXK 1024      // max buckets (N <= 262144)

static __device__ __forceinline__ void atomAddF(float* p, float v) {
    unsafeAtomicAdd(p, v);   // global_atomic_add_f32 on gfx950
}

static __device__ __forceinline__ void f4fma(float4& a, float w, const float4& u) {
    a.x = fmaf(w, u.x, a.x); a.y = fmaf(w, u.y, a.y);
    a.z = fmaf(w, u.z, a.z); a.w = fmaf(w, u.w, a.w);
}
static __device__ __forceinline__ void f4add(float4& a, const float4& u) {
    a.x += u.x; a.y += u.y; a.z += u.z; a.w += u.w;
}

// ---- pass A: bucket histogram, segmented by blockIdx&7 (~XCD) -------------
__global__ __launch_bounds__(256) void bin_count_kernel(
        const int* __restrict__ dst, int E, int* __restrict__ hist, int K) {
    __shared__ int lh[MAXK];
    int tid = threadIdx.x;
    for (int i = tid; i < K; i += 256) lh[i] = 0;
    __syncthreads();
    int stride = gridDim.x * 256;
    for (int e = blockIdx.x * 256 + tid; e < E; e += stride)
        atomicAdd(&lh[((unsigned)dst[e]) >> 8], 1);
    __syncthreads();
    int seg = blockIdx.x & 7;
    for (int b = tid; b < K; b += 256) {
        int c = lh[b];
        if (c) atomicAdd(&hist[b * 8 + seg], c);
    }
}

// ---- pass B: exclusive scan of hist[M] -> cur (append cursors) + bnd ------
__global__ __launch_bounds__(256) void scan_kernel(
        const int* __restrict__ hist, int* __restrict__ cur,
        int* __restrict__ bnd, int M, int K, int E) {
    __shared__ int part[256];
    int tid = threadIdx.x;
    int CH = (M + 255) / 256;
    int base = tid * CH;
    int s = 0;
    for (int i = 0; i < CH; ++i) {
        int idx = base + i;
        if (idx < M) s += hist[idx];
    }
    part[tid] = s;
    __syncthreads();
    if (tid < 64) {
        int carry = 0;
        for (int c = 0; c < 4; ++c) {
            int orig = part[c * 64 + tid];
            int v = orig;
            #pragma unroll
            for (int off = 1; off < 64; off <<= 1) {
                int t = __shfl_up(v, off);
                if (tid >= off) v += t;
            }
            int tot = __shfl(v, 63);
            part[c * 64 + tid] = v - orig + carry;   // exclusive
            carry += tot;
        }
    }
    __syncthreads();
    int run = part[tid];
    for (int i = 0; i < CH; ++i) {
        int idx = base + i;
        if (idx < M) {
            cur[idx] = run;
            if ((idx & 7) == 0) bnd[idx >> 3] = run;
            run += hist[idx];
        }
    }
    if (tid == 0) bnd[K] = E;
}

// ---- pass C: append (src,dst) pairs into bucket segments ------------------
__global__ __launch_bounds__(256) void fill_pairs_kernel(
        const int* __restrict__ src, const int* __restrict__ dst, int E,
        int* __restrict__ cur, int2* __restrict__ pairbuf) {
    int e = blockIdx.x * 256 + threadIdx.x;
    if (e >= E) return;
    int s = src[e], d = dst[e];
    int seg = blockIdx.x & 7;
    int pos = atomicAdd(&cur[(((unsigned)d) >> 8) * 8 + seg], 1);
    pairbuf[pos] = make_int2(s, d);
}

// ---- pass D: per-bucket CSR build + degcnt + cursor + xd (all coalesced) --
__global__ __launch_bounds__(256) void build_csr_kernel(
        const int2* __restrict__ pairbuf, const int* __restrict__ bnd,
        const int* __restrict__ x, int* __restrict__ cursor,
        int* __restrict__ degcnt, float2* __restrict__ xd,
        int* __restrict__ csr_src, int N) {
    __shared__ int cnt[256], basel[256], curl[256];
    int tid = threadIdx.x;
    int b = blockIdx.x;
    int node0 = b << 8;
    cnt[tid] = 0;
    __syncthreads();
    int bb0 = bnd[b], bb1 = bnd[b + 1];
    for (int i = bb0 + tid; i < bb1; i += 256)
        atomicAdd(&cnt[pairbuf[i].y & 255], 1);
    __syncthreads();
    if (tid < 64) {
        int carry = 0;
        for (int c = 0; c < 4; ++c) {
            int orig = cnt[c * 64 + tid];
            int v = orig;
            #pragma unroll
            for (int off = 1; off < 64; off <<= 1) {
                int t = __shfl_up(v, off);
                if (tid >= off) v += t;
            }
            int tot = __shfl(v, 63);
            basel[c * 64 + tid] = v - orig + carry;
            carry += tot;
        }
    }
    __syncthreads();
    int node = node0 + tid;
    int myBase = bb0 + basel[tid];
    curl[tid] = myBase;
    if (node < N) {
        int c = cnt[tid];
        cursor[node] = myBase;      // row begin
        degcnt[node] = c;
        xd[node] = make_float2(rsqrtf((float)c + 1.0f), __int_as_float(x[node]));
    }
    __syncthreads();
    for (int i = bb0 + tid; i < bb1; i += 256) {
        int2 p = pairbuf[i];
        int pos = atomicAdd(&curl[p.y & 255], 1);
        csr_src[pos] = p.x;
    }
}

// ---------------- layer 1: agg from embedding table, write g1 = dinv*h1 ----
__global__ __launch_bounds__(256) void layer1_kernel(
        const int* __restrict__ cursor, const int* __restrict__ deg,
        const int* __restrict__ csr_src, const float2* __restrict__ xd,
        const float4* __restrict__ table, const float* __restrict__ W,
        const float* __restrict__ bias, float* __restrict__ g1, int N) {
    __shared__ float Ws[DD * DD];   // 16 KB
    __shared__ float Hs[16 * DD];   // 4 KB
    __shared__ float dvs[16];
    int row0 = blockIdx.x * 16;
    int tid = threadIdx.x;
    {
        const float4* W4 = (const float4*)W;
        float4* Ws4 = (float4*)Ws;
        for (int k = tid; k < DD * DD / 4; k += 256) Ws4[k] = W4[k];
    }
    int node_l = tid >> 4, j = tid & 15;
    int node = row0 + node_l;
    float4 acc0 = make_float4(0.f, 0.f, 0.f, 0.f);
    float4 acc1 = acc0, acc2 = acc0, acc3 = acc0;
    if (node < N) {
        float2 sxd = xd[node];
        float di = sxd.x;
        if (j == 0) dvs[node_l] = di;
        float4 tv = table[(size_t)__float_as_int(sxd.y) * DQ + j];
        acc0.x = di * tv.x; acc0.y = di * tv.y;
        acc0.z = di * tv.z; acc0.w = di * tv.w;
        int begin = cursor[node];
        int end = begin + deg[node];
        for (int k = begin; k < end; k += 4) {
            int t0 = csr_src[k];
            int t1 = csr_src[k + 1], t2 = csr_src[k + 2], t3 = csr_src[k + 3];
            bool v1 = (k + 1 < end), v2 = (k + 2 < end), v3 = (k + 3 < end);
            int s0 = t0;
            int s1 = v1 ? t1 : node;
            int s2 = v2 ? t2 : node;
            int s3 = v3 ? t3 : node;
            float2 p0 = xd[s0], p1 = xd[s1], p2 = xd[s2], p3 = xd[s3];
            float w0 = p0.x;
            float w1 = v1 ? p1.x : 0.f;
            float w2 = v2 ? p2.x : 0.f;
            float w3 = v3 ? p3.x : 0.f;
            float4 u0 = table[(size_t)__float_as_int(p0.y) * DQ + j];
            float4 u1 = table[(size_t)__float_as_int(p1.y) * DQ + j];
            float4 u2 = table[(size_t)__float_as_int(p2.y) * DQ + j];
            float4 u3 = table[(size_t)__float_as_int(p3.y) * DQ + j];
            f4fma(acc0, w0, u0); f4fma(acc1, w1, u1);
            f4fma(acc2, w2, u2); f4fma(acc3, w3, u3);
        }
        f4add(acc0, acc1); f4add(acc2, acc3); f4add(acc0, acc2);
        acc0.x *= di; acc0.y *= di; acc0.z *= di; acc0.w *= di;
    }
    ((float4*)Hs)[node_l * DQ + j] = acc0;
    __syncthreads();

    int wave = tid >> 6, lane = tid & 63;
    float b = bias[lane];
    #pragma unroll
    for (int rr = 0; rr < 4; ++rr) {
        int row = wave * 4 + rr;
        int grow = row0 + row;
        if (grow >= N) break;
        float a = b;
        #pragma unroll
        for (int k = 0; k < DD; ++k)
            a = fmaf(Hs[row * DD + k], Ws[k * DD + lane], a);
        g1[(size_t)grow * DD + lane] = dvs[row] * fmaxf(a, 0.0f);   // g1 = dinv*h1
    }
}

// -------- layer 2 + pool: agg2 = dinv_v*(g1[v] + sum g1[s]); h2@Wlin pooled --
__global__ __launch_bounds__(256) void layer2_pool_kernel(
        const int* __restrict__ cursor, const int* __restrict__ deg,
        const int* __restrict__ csr_src, const float2* __restrict__ xd,
        const float4* __restrict__ g1, const float* __restrict__ W,
        const float* __restrict__ bias, const int* __restrict__ batch,
        const float* __restrict__ Wlin, float* __restrict__ outacc, int N) {
    __shared__ float Ws[DD * DD];
    __shared__ float Hs[16 * DD];
    __shared__ float p0s[16], p1s[16];
    __shared__ int   bat[16];
    int row0 = blockIdx.x * 16;
    int tid = threadIdx.x;
    {
        const float4* W4 = (const float4*)W;
        float4* Ws4 = (float4*)Ws;
        for (int k = tid; k < DD * DD / 4; k += 256) Ws4[k] = W4[k];
    }
    int node_l = tid >> 4, j = tid & 15;
    int node = row0 + node_l;
    float4 acc0 = make_float4(0.f, 0.f, 0.f, 0.f);
    float4 acc1 = acc0, acc2 = acc0, acc3 = acc0;
    if (node < N) {
        float di = xd[node].x;
        acc0 = g1[(size_t)node * DQ + j];    // self term, weight 1
        int begin = cursor[node];
        int end = begin + deg[node];
        for (int k = begin; k < end; k += 4) {
            int t0 = csr_src[k];
            int t1 = csr_src[k + 1], t2 = csr_src[k + 2], t3 = csr_src[k + 3];
            bool v1 = (k + 1 < end), v2 = (k + 2 < end), v3 = (k + 3 < end);
            int s1 = v1 ? t1 : node;
            int s2 = v2 ? t2 : node;
            int s3 = v3 ? t3 : node;
            float4 u0 = g1[(size_t)t0 * DQ + j];
            float4 u1 = g1[(size_t)s1 * DQ + j];
            float4 u2 = g1[(size_t)s2 * DQ + j];
            float4 u3 = g1[(size_t)s3 * DQ + j];
            f4add(acc0, u0);
            f4fma(acc1, v1 ? 1.f : 0.f, u1);
            f4fma(acc2, v2 ? 1.f : 0.f, u2);
            f4fma(acc3, v3 ? 1.f : 0.f, u3);
        }
        f4add(acc0, acc1); f4add(acc2, acc3); f4add(acc0, acc2);
        acc0.x *= di; acc0.y *= di; acc0.z *= di; acc0.w *= di;
    }
    ((float4*)Hs)[node_l * DQ + j] = acc0;
    __syncthreads();

    int wave = tid >> 6, lane = tid & 63;
    float b   = bias[lane];
    float wl0 = Wlin[lane * 2 + 0];
    float wl1 = Wlin[lane * 2 + 1];
    #pragma unroll
    for (int rr = 0; rr < 4; ++rr) {
        int row = wave * 4 + rr;
        int grow = row0 + row;
        float p0 = 0.f, p1 = 0.f;
        if (grow < N) {
            float a = b;
            #pragma unroll
            for (int k = 0; k < DD; ++k)
                a = fmaf(Hs[row * DD + k], Ws[k * DD + lane], a);
            a = fmaxf(a, 0.0f);
            p0 = a * wl0;
            p1 = a * wl1;
        }
        #pragma unroll
        for (int off = 32; off >= 1; off >>= 1) {
            p0 += __shfl_xor(p0, off);
            p1 += __shfl_xor(p1, off);
        }
        if (lane == 0) {
            p0s[row] = p0;
            p1s[row] = p1;
            bat[row] = (grow < N) ? batch[grow] : -1;
        }
    }
    __syncthreads();
    if (tid < 16) {
        int bg = bat[tid];
        bool head = (bg >= 0) && (tid == 0 || bat[tid - 1] != bg);
        if (head) {
            float s0 = 0.f, s1 = 0.f;
            for (int k = tid; k < 16 && bat[k] == bg; ++k) {
                s0 += p0s[k];
                s1 += p1s[k];
            }
            atomAddF(&outacc[bg * 2 + 0], s0);
            atomAddF(&outacc[bg * 2 + 1], s1);
        }
    }
}

// counts via binary search on sorted batch; then divide + blin
__global__ void final_kernel(const float* __restrict__ outacc,
                             const int* __restrict__ batch,
                             const float* __restrict__ blin,
                             float* __restrict__ out, int G, int N) {
    int t = blockIdx.x * blockDim.x + threadIdx.x;
    if (t >= G * 2) return;
    int g = t >> 1, c = t & 1;
    int lo = 0, hi = N;
    while (lo < hi) { int m = (lo + hi) >> 1; if (batch[m] < g) lo = m + 1; else hi = m; }
    int lo2 = lo, hi2 = N;
    while (lo2 < hi2) { int m = (lo2 + hi2) >> 1; if (batch[m] < g + 1) lo2 = m + 1; else hi2 = m; }
    float cnt = (float)(lo2 - lo);
    out[t] = outacc[t] / fmaxf(cnt, 1.0f) + blin[c];
}

extern "C" void kernel_launch(void* const* d_in, const int* in_sizes, int n_in,
                              void* d_out, int out_size, void* d_ws, size_t ws_size,
                              hipStream_t stream) {
    const int*   x      = (const int*)d_in[0];
    const int*   ei     = (const int*)d_in[1];   // [2,E] row-major
    const int*   batch  = (const int*)d_in[3];
    const float* table  = (const float*)d_in[4];
    const float* W1     = (const float*)d_in[5];
    const float* b1     = (const float*)d_in[6];
    const float* W2     = (const float*)d_in[7];
    const float* b2     = (const float*)d_in[8];
    const float* Wlin   = (const float*)d_in[9];
    const float* blin   = (const float*)d_in[10];
    float* out = (float*)d_out;

    const int N = in_sizes[0];
    const int E = in_sizes[2];          // edge_type count == E
    const int G = out_size / 2;

    const int* src = ei;
    const int* dst = ei + E;

    const int K = (N + BKT - 1) / BKT;  // buckets (<= MAXK for this problem)
    const int M = K * 8;                // (bucket, seg) cells

    // workspace layout (8-byte aligned pieces, large first)
    size_t nh = (size_t)N * DD;
    float*  g1      = (float*)d_ws;                 // N*64 f32
    int2*   pairbuf = (int2*)(g1 + nh);             // E int2
    int*    csr_src = (int*)(pairbuf + E);          // E + 16 ints (padded reads)
    int*    cursor  = csr_src + E + 16;             // N
    int*    degcnt  = cursor + N;                   // N
    float2* xd      = (float2*)(degcnt + N);        // N float2
    int*    hist    = (int*)(xd + N);               // M
    int*    cur     = hist + M;                     // M
    int*    bnd     = cur + M;                      // K+1
    float*  outacc  = (float*)(bnd + K + 2);        // 2G

    const int BT = 256;

    hipMemsetAsync(hist, 0, (size_t)M * sizeof(int), stream);
    hipMemsetAsync(outacc, 0, (size_t)G * 2 * sizeof(float), stream);

    // CSR build: histogram -> scan -> bucket append -> per-bucket sort
    bin_count_kernel<<<256, BT, 0, stream>>>(dst, E, hist, K);
    scan_kernel<<<1, BT, 0, stream>>>(hist, cur, bnd, M, K, E);
    fill_pairs_kernel<<<(E + BT - 1) / BT, BT, 0, stream>>>(src, dst, E, cur, pairbuf);
    build_csr_kernel<<<K, BT, 0, stream>>>(pairbuf, bnd, x, cursor, degcnt, xd,
                                           csr_src, N);

    // layer 1 (embed+agg+GEMM+relu fused; writes g1 = dinv*h1)
    int gRow = (N + 15) / 16;
    layer1_kernel<<<gRow, BT, 0, stream>>>(cursor, degcnt, csr_src, xd,
                                           (const float4*)table, W1, b1, g1, N);
    // layer 2 (agg+GEMM+relu+pool fused)
    layer2_pool_kernel<<<gRow, BT, 0, stream>>>(cursor, degcnt, csr_src, xd,
                                                (const float4*)g1, W2, b2,
                                                batch, Wlin, outacc, N);
    // final
    final_kernel<<<(G * 2 + BT - 1) / BT, BT, 0, stream>>>(outacc, batch, blin,
                                                           out, G, N);
}